// Round 1
// baseline (289.505 us; speedup 1.0000x reference)
//
#include <hip/hip_runtime.h>
#include <math.h>

// Problem constants: N=4, L=2048, E=512, H=8, hd=64, FORECAST=8
// M = N*L = 8192 token rows.

#define NEGV -1e30f

typedef __bf16 bf16_t;
typedef __bf16 bf16x8 __attribute__((ext_vector_type(8)));
typedef float f32x4 __attribute__((ext_vector_type(4)));

#define MFMA(a, b, c) __builtin_amdgcn_mfma_f32_16x16x32_bf16((a), (b), (c), 0, 0, 0)

// ---------------------------------------------------------------------------
// build_powers: per head h, P = I + (Xi - Xi^T); pows[h][n] = P^(n+1), f32.
// ---------------------------------------------------------------------------
__global__ __launch_bounds__(256) void build_powers(const float* __restrict__ Xi,
                                                    float* __restrict__ pows) {
  const int h = blockIdx.x;
  __shared__ __align__(16) float P[64][68];
  __shared__ __align__(16) float cur[64][68];
  const int tid = threadIdx.x;
  const float* xi = Xi + (size_t)h * 4096;
  float* dst = pows + (size_t)h * 8 * 4096;
  for (int idx = tid; idx < 4096; idx += 256) {
    const int i = idx >> 6, j = idx & 63;
    const float p = (i == j ? 1.f : 0.f) + xi[i * 64 + j] - xi[j * 64 + i];
    P[i][j] = p;
    cur[i][j] = p;
    dst[idx] = p;  // n=0 -> P^1
  }
  __syncthreads();
  const int i = tid >> 2;
  const int j0 = (tid & 3) * 16;
  for (int n = 1; n < 8; ++n) {
    float a[16];
#pragma unroll
    for (int jj = 0; jj < 16; ++jj) a[jj] = 0.f;
    for (int dd = 0; dd < 64; ++dd) {
      const float c = cur[i][dd];
#pragma unroll
      for (int jj = 0; jj < 16; ++jj) a[jj] += c * P[dd][j0 + jj];
    }
    __syncthreads();
#pragma unroll
    for (int jj = 0; jj < 16; ++jj) {
      cur[i][j0 + jj] = a[jj];
      dst[n * 4096 + i * 64 + j0 + jj] = a[jj];
    }
    __syncthreads();
  }
}

// ---------------------------------------------------------------------------
// build_B: Bmat[n][(h*64+d)][e] = sum_dd pows[h][n][d][dd] * Wo[h*64+dd][e]
// grid (4 e-tiles, 8 n, 8 h), bf16 output.
// ---------------------------------------------------------------------------
__global__ __launch_bounds__(256) void build_B(const float* __restrict__ pows,
                                               const float* __restrict__ Wo,
                                               bf16_t* __restrict__ Bmat) {
  const int et = blockIdx.x;
  const int n = blockIdx.y;
  const int h = blockIdx.z;
  __shared__ __align__(16) float P[64][68];
  __shared__ __align__(16) float We[64][128];
  const int tid = threadIdx.x;
  const float* src = pows + ((size_t)h * 8 + n) * 4096;
  for (int idx = tid; idx < 4096; idx += 256) P[idx >> 6][idx & 63] = src[idx];
  const int e0 = et * 128;
  for (int idx = tid; idx < 8192; idx += 256) {
    const int dd = idx >> 7, e = idx & 127;
    We[dd][e] = Wo[(size_t)(h * 64 + dd) * 512 + e0 + e];
  }
  __syncthreads();
  const int d = tid >> 2;
  const int eq = (tid & 3) * 32;
  float acc[32];
#pragma unroll
  for (int j = 0; j < 32; ++j) acc[j] = 0.f;
  for (int dd = 0; dd < 64; ++dd) {
    const float p = P[d][dd];
#pragma unroll
    for (int j = 0; j < 32; ++j) acc[j] += p * We[dd][eq + j];
  }
  bf16_t* dst = Bmat + (size_t)n * 512 * 512 + (size_t)(h * 64 + d) * 512 + e0 + eq;
#pragma unroll
  for (int j = 0; j < 32; ++j) dst[j] = (bf16_t)acc[j];
}

// ---------------------------------------------------------------------------
// qkv_gemm: qkv = X @ Wqkv + bqkv; scatter to q/k/v ws tensors [b][h][s][64] bf16
// 128x128 tile, BK=64, 4 waves (2x2), 16x16x32 bf16 MFMA.
// ---------------------------------------------------------------------------
__global__ __launch_bounds__(256) void qkv_gemm(const float* __restrict__ X,
                                                const float* __restrict__ W,
                                                const float* __restrict__ bias,
                                                bf16_t* __restrict__ qw,
                                                bf16_t* __restrict__ kw,
                                                bf16_t* __restrict__ vw) {
  __shared__ __align__(16) bf16_t As[128][72];
  __shared__ __align__(16) bf16_t Bs[128][72];  // transposed: [n][k]
  const int tid = threadIdx.x;
  const int wave = tid >> 6, lane = tid & 63;
  const int g = lane >> 4, li = lane & 15;
  const int row0 = blockIdx.x * 128;
  const int col0 = blockIdx.y * 128;
  const int wm = (wave >> 1) * 64, wn = (wave & 1) * 64;
  f32x4 acc[4][4] = {};
  const int m_st = tid >> 1;
  const int kh = (tid & 1) * 32;
  const int nl = tid & 127;
  const int kq = tid >> 7;
  for (int k0 = 0; k0 < 512; k0 += 64) {
    {
      const float* asrc = X + (size_t)(row0 + m_st) * 512 + k0 + kh;
#pragma unroll
      for (int c = 0; c < 4; ++c) {
        const float4 f0 = ((const float4*)asrc)[c * 2];
        const float4 f1 = ((const float4*)asrc)[c * 2 + 1];
        bf16x8 v;
        v[0] = (bf16_t)f0.x; v[1] = (bf16_t)f0.y; v[2] = (bf16_t)f0.z; v[3] = (bf16_t)f0.w;
        v[4] = (bf16_t)f1.x; v[5] = (bf16_t)f1.y; v[6] = (bf16_t)f1.z; v[7] = (bf16_t)f1.w;
        *(bf16x8*)&As[m_st][kh + c * 8] = v;
      }
      const float* bsrc = W + (size_t)(k0 + kq * 32) * 1536 + col0 + nl;
#pragma unroll
      for (int c = 0; c < 4; ++c) {
        bf16x8 v;
#pragma unroll
        for (int j = 0; j < 8; ++j) v[j] = (bf16_t)bsrc[(size_t)(c * 8 + j) * 1536];
        *(bf16x8*)&Bs[nl][kq * 32 + c * 8] = v;
      }
    }
    __syncthreads();
#pragma unroll
    for (int ks = 0; ks < 2; ++ks) {
      bf16x8 af[4], bfr[4];
#pragma unroll
      for (int mr = 0; mr < 4; ++mr)
        af[mr] = *(const bf16x8*)&As[wm + mr * 16 + li][ks * 32 + g * 8];
#pragma unroll
      for (int nr = 0; nr < 4; ++nr)
        bfr[nr] = *(const bf16x8*)&Bs[wn + nr * 16 + li][ks * 32 + g * 8];
#pragma unroll
      for (int mr = 0; mr < 4; ++mr)
#pragma unroll
        for (int nr = 0; nr < 4; ++nr)
          acc[mr][nr] = MFMA(af[mr], bfr[nr], acc[mr][nr]);
    }
    __syncthreads();
  }
  // epilogue: scatter to q/k/v [b][h][s][64]
  const int cbase = col0 + wn;            // multiple of 64
  const int sel = cbase >> 9;             // 0=q 1=k 2=v (uniform per wave)
  const int hh = (cbase & 511) >> 6;      // head (uniform per wave)
  const int bb = row0 >> 11;              // batch (uniform per block)
  bf16_t* dstp = (sel == 0 ? qw : (sel == 1 ? kw : vw)) + ((size_t)(bb * 8 + hh)) * (2048 * 64);
#pragma unroll
  for (int nr = 0; nr < 4; ++nr) {
    const int dcol = nr * 16 + li;
    const float bv = bias[cbase + dcol];
#pragma unroll
    for (int mr = 0; mr < 4; ++mr) {
#pragma unroll
      for (int i = 0; i < 4; ++i) {
        const int r = row0 + wm + mr * 16 + g * 4 + i;
        const int s = r & 2047;
        dstp[(size_t)s * 64 + dcol] = (bf16_t)(acc[mr][nr][i] + bv);
      }
    }
  }
}

// ---------------------------------------------------------------------------
// fattn: causal flash attention. grid (32 q-tiles, 8 h, 4 b), 4 waves x 16 rows.
// Writes attn_cat [b*2048+s][h*64+d] bf16.
// ---------------------------------------------------------------------------
__global__ __launch_bounds__(256) void fattn(const bf16_t* __restrict__ qw,
                                             const bf16_t* __restrict__ kw,
                                             const bf16_t* __restrict__ vw,
                                             bf16_t* __restrict__ attn) {
  __shared__ __align__(16) bf16_t Ks[64][72];
  __shared__ __align__(16) bf16_t Vt[64][72];      // transposed: [d][key]
  __shared__ __align__(16) bf16_t Ps[4][16][72];   // per-wave P tile
  const int tid = threadIdx.x;
  const int w = tid >> 6;
  const int lane = tid & 63;
  const int g = lane >> 4;
  const int li = lane & 15;
  const int qt = blockIdx.x;
  const int h = blockIdx.y;
  const int b = blockIdx.z;
  const size_t base = ((size_t)(b * 8 + h)) * (2048 * 64);
  const int q0 = qt * 64;
  const int qrow = q0 + w * 16 + li;
  const bf16x8 aq0 = *(const bf16x8*)(qw + base + (size_t)qrow * 64 + g * 8);
  const bf16x8 aq1 = *(const bf16x8*)(qw + base + (size_t)qrow * 64 + 32 + g * 8);
  f32x4 accO[4] = {};
  float m_run[4], l_run[4];
#pragma unroll
  for (int i = 0; i < 4; ++i) {
    m_run[i] = -__builtin_inff();
    l_run[i] = 0.f;
  }
  const int ntiles = qt + 1;
  const int r_st = tid >> 2;  // staging key row 0..63
  const int qu = tid & 3;     // staging quarter
  for (int kt = 0; kt < ntiles; ++kt) {
    const int kb = kt * 64;
    {
      const bf16x8* ksrc = (const bf16x8*)(kw + base + (size_t)(kb + r_st) * 64 + qu * 16);
      *(bf16x8*)&Ks[r_st][qu * 16] = ksrc[0];
      *(bf16x8*)&Ks[r_st][qu * 16 + 8] = ksrc[1];
      const bf16x8* vsrc = (const bf16x8*)(vw + base + (size_t)(kb + r_st) * 64 + qu * 16);
      const bf16x8 v0 = vsrc[0];
      const bf16x8 v1 = vsrc[1];
#pragma unroll
      for (int j = 0; j < 8; ++j) Vt[qu * 16 + j][r_st] = v0[j];
#pragma unroll
      for (int j = 0; j < 8; ++j) Vt[qu * 16 + 8 + j][r_st] = v1[j];
    }
    __syncthreads();
    // S = Q K^T (scaled), masked causal
    f32x4 sv[4];
#pragma unroll
    for (int nt = 0; nt < 4; ++nt) {
      const bf16x8 bk0 = *(const bf16x8*)&Ks[nt * 16 + li][g * 8];
      const bf16x8 bk1 = *(const bf16x8*)&Ks[nt * 16 + li][32 + g * 8];
      f32x4 z = {0.f, 0.f, 0.f, 0.f};
      z = MFMA(aq0, bk0, z);
      sv[nt] = MFMA(aq1, bk1, z);
    }
    float pmax[4];
#pragma unroll
    for (int i = 0; i < 4; ++i) pmax[i] = -__builtin_inff();
#pragma unroll
    for (int nt = 0; nt < 4; ++nt) {
      const int col = kb + nt * 16 + li;
#pragma unroll
      for (int i = 0; i < 4; ++i) {
        const int row = q0 + w * 16 + g * 4 + i;
        float x = sv[nt][i] * 0.125f;
        x = (col <= row) ? x : NEGV;
        sv[nt][i] = x;
        pmax[i] = fmaxf(pmax[i], x);
      }
    }
#pragma unroll
    for (int off = 1; off < 16; off <<= 1) {
#pragma unroll
      for (int i = 0; i < 4; ++i) pmax[i] = fmaxf(pmax[i], __shfl_xor(pmax[i], off, 64));
    }
    float scale[4], newm[4], rsum[4];
#pragma unroll
    for (int i = 0; i < 4; ++i) {
      newm[i] = fmaxf(m_run[i], pmax[i]);
      scale[i] = __expf(m_run[i] - newm[i]);
      rsum[i] = 0.f;
    }
#pragma unroll
    for (int nt = 0; nt < 4; ++nt) {
#pragma unroll
      for (int i = 0; i < 4; ++i) {
        const float p = __expf(sv[nt][i] - newm[i]);
        sv[nt][i] = p;
        rsum[i] += p;
      }
    }
#pragma unroll
    for (int off = 1; off < 16; off <<= 1) {
#pragma unroll
      for (int i = 0; i < 4; ++i) rsum[i] += __shfl_xor(rsum[i], off, 64);
    }
#pragma unroll
    for (int i = 0; i < 4; ++i) {
      l_run[i] = l_run[i] * scale[i] + rsum[i];
      m_run[i] = newm[i];
    }
#pragma unroll
    for (int nt = 0; nt < 4; ++nt) {
#pragma unroll
      for (int i = 0; i < 4; ++i) accO[nt][i] *= scale[i];
    }
    // P -> LDS (wave-private), then PV
#pragma unroll
    for (int nt = 0; nt < 4; ++nt) {
#pragma unroll
      for (int i = 0; i < 4; ++i) Ps[w][g * 4 + i][nt * 16 + li] = (bf16_t)sv[nt][i];
    }
    const bf16x8 ap0 = *(const bf16x8*)&Ps[w][li][g * 8];
    const bf16x8 ap1 = *(const bf16x8*)&Ps[w][li][32 + g * 8];
#pragma unroll
    for (int nt = 0; nt < 4; ++nt) {
      const bf16x8 bv0 = *(const bf16x8*)&Vt[nt * 16 + li][g * 8];
      const bf16x8 bv1 = *(const bf16x8*)&Vt[nt * 16 + li][32 + g * 8];
      accO[nt] = MFMA(ap0, bv0, accO[nt]);
      accO[nt] = MFMA(ap1, bv1, accO[nt]);
    }
    __syncthreads();
  }
#pragma unroll
  for (int i = 0; i < 4; ++i) {
    const int row = q0 + w * 16 + g * 4 + i;
    const float inv = 1.0f / l_run[i];
#pragma unroll
    for (int nt = 0; nt < 4; ++nt) {
      attn[(size_t)(b * 2048 + row) * 512 + h * 64 + nt * 16 + li] =
          (bf16_t)(accO[nt][i] * inv);
    }
  }
}

// ---------------------------------------------------------------------------
// out_gemm: out[b][nf][s][:] = attn_cat[b*2048+s][:] @ Bmat[nf] + bo, f32 out.
// grid (64 m-tiles, 4 col-tiles, 8 forecast)
// ---------------------------------------------------------------------------
__global__ __launch_bounds__(256) void out_gemm(const bf16_t* __restrict__ A,
                                                const bf16_t* __restrict__ Bmat,
                                                const float* __restrict__ bo,
                                                float* __restrict__ out) {
  __shared__ __align__(16) bf16_t As[128][72];
  __shared__ __align__(16) bf16_t Bs[128][72];  // transposed: [e][k]
  const int tid = threadIdx.x;
  const int wave = tid >> 6, lane = tid & 63;
  const int g = lane >> 4, li = lane & 15;
  const int row0 = blockIdx.x * 128;
  const int col0 = blockIdx.y * 128;
  const int nf = blockIdx.z;
  const bf16_t* B = Bmat + (size_t)nf * 512 * 512;
  const int wm = (wave >> 1) * 64, wn = (wave & 1) * 64;
  f32x4 acc[4][4] = {};
  const int m_st = tid >> 1;
  const int kh = (tid & 1) * 32;
  const int nl = tid & 127;
  const int kq = tid >> 7;
  for (int k0 = 0; k0 < 512; k0 += 64) {
    {
      const bf16x8* asrc = (const bf16x8*)(A + (size_t)(row0 + m_st) * 512 + k0 + kh);
#pragma unroll
      for (int c = 0; c < 4; ++c) *(bf16x8*)&As[m_st][kh + c * 8] = asrc[c];
      const bf16_t* bsrc = B + (size_t)(k0 + kq * 32) * 512 + col0 + nl;
#pragma unroll
      for (int c = 0; c < 4; ++c) {
        bf16x8 v;
#pragma unroll
        for (int j = 0; j < 8; ++j) v[j] = bsrc[(size_t)(c * 8 + j) * 512];
        *(bf16x8*)&Bs[nl][kq * 32 + c * 8] = v;
      }
    }
    __syncthreads();
#pragma unroll
    for (int ks = 0; ks < 2; ++ks) {
      bf16x8 af[4], bfr[4];
#pragma unroll
      for (int mr = 0; mr < 4; ++mr)
        af[mr] = *(const bf16x8*)&As[wm + mr * 16 + li][ks * 32 + g * 8];
#pragma unroll
      for (int nr = 0; nr < 4; ++nr)
        bfr[nr] = *(const bf16x8*)&Bs[wn + nr * 16 + li][ks * 32 + g * 8];
#pragma unroll
      for (int mr = 0; mr < 4; ++mr)
#pragma unroll
        for (int nr = 0; nr < 4; ++nr)
          acc[mr][nr] = MFMA(af[mr], bfr[nr], acc[mr][nr]);
    }
    __syncthreads();
  }
  const int bb = row0 >> 11;
  float* obase = out + ((size_t)(bb * 8 + nf)) * (2048 * 512);
#pragma unroll
  for (int nr = 0; nr < 4; ++nr) {
    const int c = col0 + wn + nr * 16 + li;
    const float bv = bo[c];
#pragma unroll
    for (int mr = 0; mr < 4; ++mr) {
#pragma unroll
      for (int i = 0; i < 4; ++i) {
        const int r = row0 + wm + mr * 16 + g * 4 + i;
        const int s = r & 2047;
        obase[(size_t)s * 512 + c] = acc[mr][nr][i] + bv;
      }
    }
  }
}

// ---------------------------------------------------------------------------
extern "C" void kernel_launch(void* const* d_in, const int* in_sizes, int n_in,
                              void* d_out, int out_size, void* d_ws, size_t ws_size,
                              hipStream_t stream) {
  const float* query = (const float*)d_in[0];
  // d_in[1]=key, d_in[2]=value are unused by the reference forward.
  const float* Wqkv = (const float*)d_in[3];
  const float* bqkv = (const float*)d_in[4];
  const float* Wo = (const float*)d_in[5];
  const float* bo = (const float*)d_in[6];
  const float* Xi = (const float*)d_in[7];
  float* out = (float*)d_out;

  char* ws = (char*)d_ws;
  bf16_t* qw = (bf16_t*)(ws + 0);                 // [4][8][2048][64] bf16 = 8 MiB
  bf16_t* kw = (bf16_t*)(ws + 8388608);           // 8 MiB
  bf16_t* vw = (bf16_t*)(ws + 16777216);          // 8 MiB
  bf16_t* attn = (bf16_t*)(ws + 25165824);        // [8192][512] bf16 = 8 MiB
  bf16_t* Bmat = (bf16_t*)(ws + 33554432);        // [8][512][512] bf16 = 4 MiB
  float* pows = (float*)(ws + 37748736);          // [8][8][64][64] f32 = 1 MiB

  build_powers<<<dim3(8), dim3(256), 0, stream>>>(Xi, pows);
  build_B<<<dim3(4, 8, 8), dim3(256), 0, stream>>>(pows, Wo, Bmat);
  qkv_gemm<<<dim3(64, 12), dim3(256), 0, stream>>>(query, Wqkv, bqkv, qw, kw, vw);
  fattn<<<dim3(32, 8, 4), dim3(256), 0, stream>>>(qw, kw, vw, attn);
  out_gemm<<<dim3(64, 4, 8), dim3(256), 0, stream>>>(attn, Bmat, bo, out);
}